// Round 4
// baseline (765.555 us; speedup 1.0000x reference)
//
#include <hip/hip_runtime.h>
#include <hip/hip_bf16.h>

typedef _Float16 half8 __attribute__((ext_vector_type(8)));
typedef float f32x4 __attribute__((ext_vector_type(4)));

#define NN 50000
#define NE 800000
#define TE 64
#define SCAN_T 1024
#define CHUNK 49   // ceil(NN / SCAN_T)

// ---------------------------------------------------------------------------
// Repack W3 [64][256] (k, 4f+l) -> fragment-ordered f16 W3re for MFMA B-frags.
// w3p[((ks*4+nt)*64 + lane)*8 + u] = W3[j>>2][4*f + (j&3)]
//   j = 32*ks + 8*(lane>>4) + u,  f = 16*nt + (lane&15)
// ---------------------------------------------------------------------------
__global__ void pack_w3_kernel(const float* __restrict__ W3, _Float16* __restrict__ w3p) {
  int t = blockIdx.x * blockDim.x + threadIdx.x;
  if (t >= 8 * 4 * 64) return;
  int lane = t & 63;
  int nt   = (t >> 6) & 3;
  int ks   = t >> 8;
  int f    = 16 * nt + (lane & 15);
  int jbase = 32 * ks + 8 * (lane >> 4);
#pragma unroll
  for (int u = 0; u < 8; ++u) {
    int j = jbase + u;
    w3p[t * 8 + u] = (_Float16)W3[(j >> 2) * 256 + 4 * f + (j & 3)];
  }
}

// ---------------------------------------------------------------------------
// CSR build: histogram -> exclusive scan -> scatter sorted edge ids
// ---------------------------------------------------------------------------
__global__ void hist_kernel(const int* __restrict__ rcv, int* __restrict__ deg) {
  int e = blockIdx.x * blockDim.x + threadIdx.x;
  if (e < NE) atomicAdd(&deg[rcv[e]], 1);
}

__global__ __launch_bounds__(SCAN_T)
void scan_kernel(const int* __restrict__ deg, int* __restrict__ pos) {
  __shared__ int s[SCAN_T];
  const int t = threadIdx.x;
  const int base = t * CHUNK;
  int sum = 0;
  for (int j = 0; j < CHUNK; ++j) {
    int i = base + j;
    if (i < NN) sum += deg[i];
  }
  s[t] = sum;
  __syncthreads();
  for (int d = 1; d < SCAN_T; d <<= 1) {
    int v = (t >= d) ? s[t - d] : 0;
    __syncthreads();
    s[t] += v;
    __syncthreads();
  }
  int run = s[t] - sum;   // exclusive prefix of this chunk
  for (int j = 0; j < CHUNK; ++j) {
    int i = base + j;
    if (i < NN) { pos[i] = run; run += deg[i]; }
  }
}

__global__ void scatter_kernel(const int* __restrict__ rcv, int* __restrict__ pos,
                               int* __restrict__ eidx) {
  int e = blockIdx.x * blockDim.x + threadIdx.x;
  if (e < NE) {
    int slot = atomicAdd(&pos[rcv[e]], 1);
    eidx[slot] = e;
  }
}

// ---------------------------------------------------------------------------
// Y[row, lane] = scale * sum_k X[row, k] * W[k, lane]   (64x64 weight)
// ---------------------------------------------------------------------------
__global__ __launch_bounds__(256)
void linear64_kernel(const float* __restrict__ X, const float* __restrict__ W,
                     float* __restrict__ Y, float scale, int nrows) {
  int gid  = blockIdx.x * 256 + (int)threadIdx.x;
  int row  = gid >> 6;
  int lane = threadIdx.x & 63;
  if (row >= nrows) return;
  const float* xr = X + (long)row * 64;
  float acc = 0.f;
#pragma unroll
  for (int k = 0; k < 64; ++k) acc = fmaf(xr[k], W[k * 64 + lane], acc);
  Y[(long)row * 64 + lane] = acc * scale;
}

__device__ __forceinline__ float swishf(float v) {
  return v / (1.f + __expf(-v));
}

// ---------------------------------------------------------------------------
// Fused edge kernel over RECEIVER-SORTED edges: 64 edges/block, 4 waves.
//  h1 = swish(r @ W1); h2 = swish(h1 @ W2)        (fp32 VALU, h2 stored f16)
//  msg = (A' @ W3re) * x_s                        (f16 MFMA, K=256)
//  msg rows -> LDS; wave-local segmented sum over receiver runs;
//  one atomicAdd row per run within each wave's 16-row window
//  (window tails ALWAYS flushed -- partial-run atomics are correct).
// ---------------------------------------------------------------------------
__global__ __launch_bounds__(256, 4)
void edge_kernel(const float* __restrict__ xup, const float* __restrict__ ef,
                 const float* __restrict__ rad, const int* __restrict__ senders,
                 const int* __restrict__ receivers, const int* __restrict__ mask,
                 const float* __restrict__ W1, const float* __restrict__ W2,
                 const _Float16* __restrict__ w3p, const int* __restrict__ eidx,
                 float* __restrict__ agg) {
  __shared__ float    s_r[TE][9];      // 2304 B
  __shared__ float    s_ef[TE][4];     // 1024 B
  __shared__ _Float16 s_xs[TE][66];    // 8448 B  (x[senders]*mask, f16)
  __shared__ float    s_msg[TE][65];   // 16640 B (h1 early, msg rows later)
  __shared__ _Float16 s_h2[TE][66];    // 8448 B
  __shared__ int      s_recv[TE];
  __shared__ int      s_eid[TE];

  const int t  = threadIdx.x;
  const long p0 = (long)blockIdx.x * TE;

  if (t < TE) {
    const int eid = eidx[p0 + t];
    s_eid[t]  = eid;
    s_recv[t] = receivers[eid];
  }
  __syncthreads();

  // ---- stage radial / edge-attrs via sorted ids ----
  for (int i = t; i < TE * 8; i += 256) {
    const int e = i >> 3;
    s_r[e][i & 7] = rad[(long)s_eid[e] * 8 + (i & 7)];
  }
  {
    const int e = t >> 2, l = t & 3;
    s_ef[e][l] = ef[(long)s_eid[e] * 4 + l];
  }
  // ---- gather x[senders] * mask -> s_xs f16 (4 threads per edge) ----
  {
    const int e  = t >> 2;
    const int c0 = (t & 3) * 16;
    const int eid = s_eid[e];
    const int sn  = senders[eid];
    const float m = mask[eid] ? 1.0f : 0.0f;
    const float4* src = reinterpret_cast<const float4*>(xup + (long)sn * 64 + c0);
#pragma unroll
    for (int q = 0; q < 4; ++q) {
      float4 v = src[q];
      s_xs[e][c0 + 4 * q + 0] = (_Float16)(v.x * m);
      s_xs[e][c0 + 4 * q + 1] = (_Float16)(v.y * m);
      s_xs[e][c0 + 4 * q + 2] = (_Float16)(v.z * m);
      s_xs[e][c0 + 4 * q + 3] = (_Float16)(v.w * m);
    }
  }
  __syncthreads();

  // ---- h1 = swish(r @ W1) -> s_msg (used as h1 buffer here) ----
  {
    const int e  = t & 63;
    const int c0 = (t >> 6) * 16;
    float rv[8];
#pragma unroll
    for (int k = 0; k < 8; ++k) rv[k] = s_r[e][k];
#pragma unroll
    for (int cc = 0; cc < 16; ++cc) {
      float acc = 0.f;
#pragma unroll
      for (int k = 0; k < 8; ++k) acc = fmaf(rv[k], W1[k * 64 + c0 + cc], acc);
      s_msg[e][c0 + cc] = swishf(acc);
    }
  }
  __syncthreads();

  // ---- h2 = swish(h1 @ W2) -> s_h2 (f16) ----
  {
    const int e  = t & 63;
    const int c0 = (t >> 6) * 16;
    float acc[16];
#pragma unroll
    for (int cc = 0; cc < 16; ++cc) acc[cc] = 0.f;
    for (int k = 0; k < 64; ++k) {
      const float h = s_msg[e][k];
      const float4* w2r = reinterpret_cast<const float4*>(W2 + k * 64 + c0);
#pragma unroll
      for (int q = 0; q < 4; ++q) {
        float4 wv = w2r[q];
        acc[4 * q + 0] = fmaf(h, wv.x, acc[4 * q + 0]);
        acc[4 * q + 1] = fmaf(h, wv.y, acc[4 * q + 1]);
        acc[4 * q + 2] = fmaf(h, wv.z, acc[4 * q + 2]);
        acc[4 * q + 3] = fmaf(h, wv.w, acc[4 * q + 3]);
      }
    }
#pragma unroll
    for (int cc = 0; cc < 16; ++cc) s_h2[e][c0 + cc] = (_Float16)swishf(acc[cc]);
  }
  __syncthreads();

  // ---- stage 3: msg = (A' @ W3re) * x_s via f16 MFMA 16x16x32, K=256 ----
  {
    const int w    = t >> 6;        // wave = 16-edge M-tile
    const int lane = t & 63;
    const int m    = lane & 15;
    const int g    = lane >> 4;
    const int e_m  = w * 16 + m;

    float ef4[4];
#pragma unroll
    for (int l = 0; l < 4; ++l) ef4[l] = s_ef[e_m][l];

    f32x4 acc[4];
#pragma unroll
    for (int nt = 0; nt < 4; ++nt) acc[nt] = (f32x4){0.f, 0.f, 0.f, 0.f};

#pragma unroll
    for (int ks = 0; ks < 8; ++ks) {
      const int kk0 = 8 * ks + 2 * g;
      const float h0  = (float)s_h2[e_m][kk0];
      const float h1v = (float)s_h2[e_m][kk0 + 1];
      half8 a;
#pragma unroll
      for (int l = 0; l < 4; ++l) {
        a[l]     = (_Float16)(h0 * ef4[l]);
        a[4 + l] = (_Float16)(h1v * ef4[l]);
      }
#pragma unroll
      for (int nt = 0; nt < 4; ++nt) {
        half8 b = *reinterpret_cast<const half8*>(w3p + ((size_t)(ks * 4 + nt) * 64 + lane) * 8);
        acc[nt] = __builtin_amdgcn_mfma_f32_16x16x32_f16(a, b, acc[nt], 0, 0, 0);
      }
    }

    // ---- epilogue: msg rows -> LDS (s_msg free after h2) ----
    const int col = lane & 15;
    const int rg  = lane >> 4;
#pragma unroll
    for (int nt = 0; nt < 4; ++nt) {
      const int f = nt * 16 + col;
#pragma unroll
      for (int i = 0; i < 4; ++i) {
        const int e_row = w * 16 + rg * 4 + i;
        s_msg[e_row][f] = acc[nt][i] * (float)s_xs[e_row][f];
      }
    }
    __syncthreads();

    // ---- segmented sum over receiver runs; wave w owns rows [16w,16w+16).
    //      FLUSH at window end (rr==15) even mid-run: partial sums are safe.
    {
      const int f = lane;
      float v = 0.f;
#pragma unroll
      for (int rr = 0; rr < 16; ++rr) {
        const int r = w * 16 + rr;
        v += s_msg[r][f];
        const bool last = (rr == 15) || (s_recv[r + 1] != s_recv[r]);
        if (last) {
          unsafeAtomicAdd(&agg[(size_t)s_recv[r] * 64 + f], v);
          v = 0.f;
        }
      }
    }
  }
}

extern "C" void kernel_launch(void* const* d_in, const int* in_sizes, int n_in,
                              void* d_out, int out_size, void* d_ws, size_t ws_size,
                              hipStream_t stream) {
  const float*  nf    = (const float*)d_in[0];
  const float*  ef    = (const float*)d_in[1];
  const float*  rad   = (const float*)d_in[2];
  const int*    snd   = (const int*)d_in[3];
  const int*    rcv   = (const int*)d_in[4];
  const int*    msk   = (const int*)d_in[5];
  const float*  W_up  = (const float*)d_in[6];
  const float*  W1    = (const float*)d_in[7];
  const float*  W2    = (const float*)d_in[8];
  const float*  W3    = (const float*)d_in[9];
  const float*  W_dn  = (const float*)d_in[10];
  float* out = (float*)d_out;

  // workspace layout (~29.3 MB)
  float*    agg  = (float*)d_ws;                          // 12.8 MB
  float*    xbuf = agg + (size_t)NN * 64;                 // 12.8 MB
  _Float16* w3p  = (_Float16*)(xbuf + (size_t)NN * 64);   // 32 KB
  int*      deg  = (int*)(w3p + 16384);                   // 200 KB
  int*      pos  = deg + NN;                              // 200 KB
  int*      eidx = pos + NN;                              // 3.2 MB

  hipMemsetAsync(agg, 0, (size_t)NN * 64 * sizeof(float), stream);
  hipMemsetAsync(deg, 0, (size_t)NN * sizeof(int), stream);

  pack_w3_kernel<<<8, 256, 0, stream>>>(W3, w3p);

  // CSR build: histogram -> scan -> scatter
  hist_kernel<<<(NE + 255) / 256, 256, 0, stream>>>(rcv, deg);
  scan_kernel<<<1, SCAN_T, 0, stream>>>(deg, pos);
  scatter_kernel<<<(NE + 255) / 256, 256, 0, stream>>>(rcv, pos, eidx);

  // x = nf @ W_up
  linear64_kernel<<<(NN * 64) / 256, 256, 0, stream>>>(nf, W_up, xbuf, 1.0f, NN);

  // fused edge MLP + tensor product + run-compacted scatter
  edge_kernel<<<NE / TE, 256, 0, stream>>>(xbuf, ef, rad, snd, rcv, msk,
                                           W1, W2, w3p, eidx, agg);

  // out = (agg / 16) @ W_down
  linear64_kernel<<<(NN * 64) / 256, 256, 0, stream>>>(agg, W_dn, out, 1.0f / 16.0f, NN);
}

// Round 6
// 355.459 us; speedup vs baseline: 2.1537x; 2.1537x over previous
//
#include <hip/hip_runtime.h>
#include <hip/hip_bf16.h>

typedef _Float16 half8 __attribute__((ext_vector_type(8)));
typedef _Float16 half2v __attribute__((ext_vector_type(2)));
typedef float f32x4 __attribute__((ext_vector_type(4)));

#define NN 50000
#define NE 800000

__device__ __forceinline__ float swishf(float v) { return v / (1.f + __expf(-v)); }

// ---------------------------------------------------------------------------
// Pack W3 [64][256] and W2 [64][64] into MFMA-B fragment order (f16).
// w3p[t*8+u] = W3[j>>2][4*f+(j&3)],  j=32ks+8(lane>>4)+u, f=16nt+(lane&15)
// w2p[t*8+u] = W2[32kk+8(lane>>4)+u][16nt+(lane&15)]
// ---------------------------------------------------------------------------
__global__ void pack_kernel(const float* __restrict__ W3, const float* __restrict__ W2,
                            _Float16* __restrict__ w3p, _Float16* __restrict__ w2p) {
  const int b = blockIdx.x, tid = threadIdx.x;
  if (b < 8) {
    int t = b * 256 + tid;               // 0..2047
    int lane = t & 63, nt = (t >> 6) & 3, ks = t >> 8;
    int f = 16 * nt + (lane & 15);
    int jb = 32 * ks + 8 * (lane >> 4);
#pragma unroll
    for (int u = 0; u < 8; ++u) {
      int j = jb + u;
      w3p[t * 8 + u] = (_Float16)W3[(j >> 2) * 256 + 4 * f + (j & 3)];
    }
  } else {
    int t = (b - 8) * 256 + tid;         // 0..511
    if (t < 512) {
      int lane = t & 63, nt = (t >> 6) & 3, kk = t >> 8;
      int c = 16 * nt + (lane & 15);
      int kb = 32 * kk + 8 * (lane >> 4);
#pragma unroll
      for (int u = 0; u < 8; ++u)
        w2p[t * 8 + u] = (_Float16)W2[(kb + u) * 64 + c];
    }
  }
}

// ---------------------------------------------------------------------------
// Y[row] = X[row] @ W   (64x64), f16 output (linear_up)
// ---------------------------------------------------------------------------
__global__ __launch_bounds__(256)
void linear_up_kernel(const float* __restrict__ X, const float* __restrict__ W,
                      _Float16* __restrict__ Y) {
  int gid = blockIdx.x * 256 + (int)threadIdx.x;
  int row = gid >> 6;
  int lane = threadIdx.x & 63;
  const float* xr = X + (long)row * 64;
  float acc = 0.f;
#pragma unroll
  for (int k = 0; k < 64; ++k) acc = fmaf(xr[k], W[k * 64 + lane], acc);
  Y[(long)row * 64 + lane] = (_Float16)acc;
}

// Y[row] = scale * X[row] @ W  (f32 out, linear_down)
__global__ __launch_bounds__(256)
void linear_down_kernel(const float* __restrict__ X, const float* __restrict__ W,
                        float* __restrict__ Y, float scale) {
  int gid = blockIdx.x * 256 + (int)threadIdx.x;
  int row = gid >> 6;
  int lane = threadIdx.x & 63;
  const float* xr = X + (long)row * 64;
  float acc = 0.f;
#pragma unroll
  for (int k = 0; k < 64; ++k) acc = fmaf(xr[k], W[k * 64 + lane], acc);
  Y[(long)row * 64 + lane] = acc * scale;
}

// ---------------------------------------------------------------------------
// Radial MLP, streaming: h1 = swish(r@W1) (VALU), h2 = swish(h1@W2) (f16 MFMA).
// Output h2p rows in permuted layout pos(ch) = 16*((ch>>1)&3) + 2*(ch>>3) + (ch&1)
// so tp_kernel reads per-lane A-frag pairs as contiguous 16B loads.
// h2p indexed CHUNK-relative (blockIdx), inputs by absolute edge id.
// ---------------------------------------------------------------------------
__global__ __launch_bounds__(256, 4)
void radial_kernel(const float* __restrict__ rad, const float* __restrict__ W1,
                   const _Float16* __restrict__ w2p, _Float16* __restrict__ h2p,
                   int e_base) {
  __shared__ float    s_r[64][9];
  __shared__ _Float16 s_h1[64][72];
  __shared__ _Float16 s_hp[64][72];

  const int t = threadIdx.x;
  const long e0 = (long)e_base + (long)blockIdx.x * 64;

  for (int i = t; i < 512; i += 256) s_r[i >> 3][i & 7] = rad[e0 * 8 + i];
  __syncthreads();

  // h1 = swish(r @ W1): thread (e, 16 channels), W1 reads wave-uniform
  {
    const int e = t & 63, c0 = (t >> 6) * 16;
    float rv[8];
#pragma unroll
    for (int k = 0; k < 8; ++k) rv[k] = s_r[e][k];
#pragma unroll
    for (int p = 0; p < 8; ++p) {
      float a0 = 0.f, a1 = 0.f;
#pragma unroll
      for (int k = 0; k < 8; ++k) {
        a0 = fmaf(rv[k], W1[k * 64 + c0 + 2 * p], a0);
        a1 = fmaf(rv[k], W1[k * 64 + c0 + 2 * p + 1], a1);
      }
      half2v h = { (_Float16)swishf(a0), (_Float16)swishf(a1) };
      *reinterpret_cast<half2v*>(&s_h1[e][c0 + 2 * p]) = h;
    }
  }
  __syncthreads();

  // h2 = swish(h1 @ W2) via f16 MFMA 16x16x32 (wave = 16 edges x 64 ch)
  {
    const int w = t >> 6, lane = t & 63, m = lane & 15, g = lane >> 4;
    f32x4 acc[4];
#pragma unroll
    for (int nt = 0; nt < 4; ++nt) acc[nt] = (f32x4){0.f, 0.f, 0.f, 0.f};
#pragma unroll
    for (int kk = 0; kk < 2; ++kk) {
      half8 a = *reinterpret_cast<const half8*>(&s_h1[w * 16 + m][32 * kk + 8 * g]);
#pragma unroll
      for (int nt = 0; nt < 4; ++nt) {
        half8 bfr = *reinterpret_cast<const half8*>(w2p + ((size_t)(kk * 4 + nt) * 64 + lane) * 8);
        acc[nt] = __builtin_amdgcn_mfma_f32_16x16x32_f16(a, bfr, acc[nt], 0, 0, 0);
      }
    }
    const int col = lane & 15, rg = lane >> 4;
    const int pbase = 16 * ((col >> 1) & 3) + 2 * (col >> 3) + (col & 1);
#pragma unroll
    for (int nt = 0; nt < 4; ++nt) {
      const int pos = pbase + 4 * nt;
#pragma unroll
      for (int i = 0; i < 4; ++i) {
        const int erow = w * 16 + rg * 4 + i;
        s_hp[erow][pos] = (_Float16)swishf(acc[nt][i]);
      }
    }
  }
  __syncthreads();

  // coalesced copy-out: 64 rows x 128B  (16 halves = 2x uint4 per thread)
  {
    const int row = t >> 2, seg = t & 3;
    uint4 v0 = *reinterpret_cast<const uint4*>(&s_hp[row][seg * 16]);
    uint4 v1 = *reinterpret_cast<const uint4*>(&s_hp[row][seg * 16 + 8]);
    _Float16* dst = h2p + ((long)blockIdx.x * 64 + row) * 64 + seg * 16;
    *reinterpret_cast<uint4*>(dst) = v0;
    *reinterpret_cast<uint4*>(dst + 8) = v1;
  }
}

// ---------------------------------------------------------------------------
// TP + scatter, streaming edge order: msg = (A' @ W3re) * x_s, atomicAdd agg.
// A'[e][4k+l] = h2[e][k]*ef[e][l] built in registers from h2p frag pairs.
// One barrier. h2p chunk-relative, everything else absolute.
// ---------------------------------------------------------------------------
__global__ __launch_bounds__(256, 4)
void tp_kernel(const _Float16* __restrict__ xup, const float* __restrict__ ef,
               const _Float16* __restrict__ h2p, const int* __restrict__ senders,
               const int* __restrict__ receivers, const int* __restrict__ mask,
               const _Float16* __restrict__ w3p, float* __restrict__ agg,
               int e_base) {
  __shared__ float    s_ef[64][4];
  __shared__ _Float16 s_xs[64][72];
  __shared__ int      s_recv[64];

  const int t = threadIdx.x;
  const long e0 = (long)e_base + (long)blockIdx.x * 64;
  const int w = t >> 6, lane = t & 63, m = lane & 15, g = lane >> 4;

  // per-lane h2 A-frag source: 32B contiguous (pairs for ks=0..7 at this g)
  const _Float16* hrow = h2p + ((long)blockIdx.x * 64 + w * 16 + m) * 64 + g * 16;
  half8 hlo = *reinterpret_cast<const half8*>(hrow);
  half8 hhi = *reinterpret_cast<const half8*>(hrow + 8);

  // stage ef / x_s / receivers
  s_ef[t >> 2][t & 3] = ef[e0 * 4 + t];
  {
    const int e = t >> 2, q = t & 3;
    const int sn = senders[e0 + e];
    const int mk = mask[e0 + e];
    uint4 v0 = {0, 0, 0, 0}, v1 = {0, 0, 0, 0};
    if (mk) {
      const uint4* src = reinterpret_cast<const uint4*>(xup + (long)sn * 64 + q * 16);
      v0 = src[0]; v1 = src[1];
    }
    *reinterpret_cast<uint4*>(&s_xs[e][q * 16]) = v0;
    *reinterpret_cast<uint4*>(&s_xs[e][q * 16 + 8]) = v1;
  }
  if (t < 64) s_recv[t] = receivers[e0 + t];
  __syncthreads();

  const int e_m = w * 16 + m;
  float ef4[4];
#pragma unroll
  for (int l = 0; l < 4; ++l) ef4[l] = s_ef[e_m][l];

  f32x4 acc[4];
#pragma unroll
  for (int nt = 0; nt < 4; ++nt) acc[nt] = (f32x4){0.f, 0.f, 0.f, 0.f};

#pragma unroll
  for (int ks = 0; ks < 8; ++ks) {
    const float h0  = (float)(ks < 4 ? hlo[2 * ks]     : hhi[2 * (ks - 4)]);
    const float h1v = (float)(ks < 4 ? hlo[2 * ks + 1] : hhi[2 * (ks - 4) + 1]);
    half8 a;
#pragma unroll
    for (int l = 0; l < 4; ++l) {
      a[l]     = (_Float16)(h0 * ef4[l]);
      a[4 + l] = (_Float16)(h1v * ef4[l]);
    }
#pragma unroll
    for (int nt = 0; nt < 4; ++nt) {
      half8 bfr = *reinterpret_cast<const half8*>(w3p + ((size_t)(ks * 4 + nt) * 64 + lane) * 8);
      acc[nt] = __builtin_amdgcn_mfma_f32_16x16x32_f16(a, bfr, acc[nt], 0, 0, 0);
    }
  }

  // epilogue: multiply x_s, scatter
  const int col = lane & 15, rg = lane >> 4;
#pragma unroll
  for (int nt = 0; nt < 4; ++nt) {
    const int f = nt * 16 + col;
#pragma unroll
    for (int i = 0; i < 4; ++i) {
      const int e_row = w * 16 + rg * 4 + i;
      const float v = acc[nt][i] * (float)s_xs[e_row][f];
      unsafeAtomicAdd(&agg[(size_t)s_recv[e_row] * 64 + f], v);
    }
  }
}

extern "C" void kernel_launch(void* const* d_in, const int* in_sizes, int n_in,
                              void* d_out, int out_size, void* d_ws, size_t ws_size,
                              hipStream_t stream) {
  const float* nf   = (const float*)d_in[0];
  const float* ef   = (const float*)d_in[1];
  const float* rad  = (const float*)d_in[2];
  const int*   snd  = (const int*)d_in[3];
  const int*   rcv  = (const int*)d_in[4];
  const int*   msk  = (const int*)d_in[5];
  const float* W_up = (const float*)d_in[6];
  const float* W1   = (const float*)d_in[7];
  const float* W2   = (const float*)d_in[8];
  const float* W3   = (const float*)d_in[9];
  const float* W_dn = (const float*)d_in[10];
  float* out = (float*)d_out;

  // workspace layout
  float*    agg  = (float*)d_ws;                          // 12.8 MB
  _Float16* xbuf = (_Float16*)(agg + (size_t)NN * 64);    // 6.4 MB
  _Float16* w3p  = xbuf + (size_t)NN * 64;                // 32 KB
  _Float16* w2p  = w3p + 2048 * 8;                        // 8 KB
  _Float16* h2p  = w2p + 512 * 8;                         // remainder: chunked h2
  const size_t fixed = (size_t)((char*)h2p - (char*)d_ws);

  // chunk size from remaining workspace (128 B per edge), multiple of 64 edges
  long ce = (ws_size > fixed) ? (long)((ws_size - fixed) / 128) : 0;
  ce = (ce / 64) * 64;
  if (ce > NE) ce = NE;
  if (ce < 64) ce = 64;   // assume ws_size ample (>=29 MB observed)

  hipMemsetAsync(agg, 0, (size_t)NN * 64 * sizeof(float), stream);
  pack_kernel<<<10, 256, 0, stream>>>(W3, W2, w3p, w2p);
  linear_up_kernel<<<(NN * 64) / 256, 256, 0, stream>>>(nf, W_up, xbuf);

  for (long b = 0; b < NE; b += ce) {
    const long cnt = (NE - b < ce) ? (NE - b) : ce;
    const int nblk = (int)(cnt / 64);
    radial_kernel<<<nblk, 256, 0, stream>>>(rad, W1, w2p, h2p, (int)b);
    tp_kernel<<<nblk, 256, 0, stream>>>(xbuf, ef, h2p, snd, rcv, msk, w3p, agg, (int)b);
  }

  linear_down_kernel<<<(NN * 64) / 256, 256, 0, stream>>>(agg, W_dn, out, 1.0f / 16.0f);
}